// Round 6
// baseline (134.891 us; speedup 1.0000x reference)
//
#include <hip/hip_runtime.h>

#define EPS 1e-5f

typedef __attribute__((ext_vector_type(8))) __bf16 bf16x8;
typedef __attribute__((ext_vector_type(4))) float f32x4;

__device__ __forceinline__ float silu_f(float v) {
  return v / (1.f + __expf(-v));
}

// ---------------- prep: fold BN + scales ----------------
__global__ __launch_bounds__(256) void prep_kernel(
    const float* __restrict__ w_experts, const float* __restrict__ bn_gamma,
    const float* __restrict__ bn_beta, const float* __restrict__ bn_mean,
    const float* __restrict__ bn_var, const float* __restrict__ scales,
    const float* __restrict__ w_out, const float* __restrict__ out_gamma,
    const float* __restrict__ out_beta, const float* __restrict__ out_mean,
    const float* __restrict__ out_var,
    float* __restrict__ eff_kernel, float* __restrict__ eff_bias,
    __bf16* __restrict__ w_eff, float* __restrict__ bias2)
{
  const int t = threadIdx.x;
  if (blockIdx.x == 0) {
    const int c = t;
    float k9[9];
#pragma unroll
    for (int r = 0; r < 9; ++r) k9[r] = 0.f;
    float bias = 0.f;
    for (int e = 0; e < 9; ++e) {
      const int ec = e * 256 + c;
      const float tt = bn_gamma[ec] * rsqrtf(bn_var[ec] + EPS);
      const float sc = scales[ec];
      const float es = tt * sc;
      bias += (bn_beta[ec] - bn_mean[ec] * tt) * sc;
      const float* wp = w_experts + (size_t)ec * 9;
#pragma unroll
      for (int r = 0; r < 9; ++r) k9[r] += es * wp[r];
    }
#pragma unroll
    for (int r = 0; r < 9; ++r) eff_kernel[c * 9 + r] = k9[r];
    eff_bias[c] = bias;
    const float t2 = out_gamma[c] * rsqrtf(out_var[c] + EPS);
    bias2[c] = out_beta[c] - out_mean[c] * t2;
  } else {
    const int i = (blockIdx.x - 1) * 256 + t;   // 0..65535
    const int o = i >> 8;
    const float t2 = out_gamma[o] * rsqrtf(out_var[o] + EPS);
    w_eff[i] = (__bf16)(w_out[i] * t2);
  }
}

// ---------------- fused: depthwise 3x3 + SiLU -> LDS -> MFMA out-proj -------
// grid 1024 = (b & 7 | (half,h) << 3): half-row blocks (32 px), 512 threads.
// LDS ~26KB + launch_bounds(512,8) -> 4 blocks/CU = 32 waves/CU.
#define BSTRIDE 258   // pixel stride in B_lds (129 dw === 1 mod 8: conflict-free writes)
__global__ __launch_bounds__(512, 8) void fused_kernel(
    const float* __restrict__ x, const float* __restrict__ eff_kernel,
    const float* __restrict__ eff_bias, const __bf16* __restrict__ w_eff,
    const float* __restrict__ bias2, float* __restrict__ out)
{
  __shared__ __align__(16) __bf16 B_lds[32 * BSTRIDE];  // [local pixel][ch]
  __shared__ float kern_s[256 * 9];
  __shared__ float bias_s[256];
  const int t = threadIdx.x;
  const int id = blockIdx.x;
  const int b = id & 7;                 // XCD-local batch
  const int rest = id >> 3;             // 0..127
  const int h = rest >> 1;              // 0..63
  const int half = rest & 1;            // 0/1 -> pixel offset 0/32

  for (int i = t; i < 2304; i += 512) kern_s[i] = eff_kernel[i];
  if (t < 256) bias_s[t] = eff_bias[t];
  __syncthreads();

  const int lane = t & 63;
  const int wv = t >> 6;                // 0..7
  const int chl = lane >> 3;            // 0..7 channel sub-index
  const int pxl = lane & 7;             // 0..7, each covers 4 px via float4
  const int w0 = half * 32 + pxl * 4;   // global w of first pixel
  const bool up_ok = (h > 0), dn_ok = (h < 63);
  const bool left_ok = (w0 > 0), right_ok = (w0 + 4 < 64);

#pragma unroll
  for (int it = 0; it < 4; ++it) {
    const int ch = it * 64 + wv * 8 + chl;           // 0..255
    const float* xc = x + (size_t)(b * 256 + ch) * 4096;

    float rowv[3][6];
#pragma unroll
    for (int r = 0; r < 3; ++r) {
      const int hh = h + r - 1;
      if ((r == 0 && !up_ok) || (r == 2 && !dn_ok)) {
#pragma unroll
        for (int q = 0; q < 6; ++q) rowv[r][q] = 0.f;
      } else {
        const float* xr = xc + hh * 64;
        const float4 m = *(const float4*)(xr + w0);
        rowv[r][0] = left_ok ? xr[w0 - 1] : 0.f;     // direct neighbor loads
        rowv[r][1] = m.x;  rowv[r][2] = m.y;
        rowv[r][3] = m.z;  rowv[r][4] = m.w;
        rowv[r][5] = right_ok ? xr[w0 + 4] : 0.f;    // (no shfl: L1-hot lines)
      }
    }

    float k[9];
#pragma unroll
    for (int j = 0; j < 9; ++j) k[j] = kern_s[ch * 9 + j];
    const float bias = bias_s[ch];

#pragma unroll
    for (int j = 0; j < 4; ++j) {
      float s = bias;
#pragma unroll
      for (int r = 0; r < 3; ++r)
        s += k[r * 3] * rowv[r][j] + k[r * 3 + 1] * rowv[r][j + 1] + k[r * 3 + 2] * rowv[r][j + 2];
      B_lds[(pxl * 4 + j) * BSTRIDE + ch] = (__bf16)silu_f(s);
    }
  }
  __syncthreads();

  // ---- GEMM phase: M=256(o) x N=32(p) x K=256(c); 8 waves of 32(o) x 32(p)
  const int quad = lane >> 4, l15 = lane & 15;
  const int wave_o = wv * 32;

  f32x4 acc[2][2];
#pragma unroll
  for (int i = 0; i < 2; ++i)
#pragma unroll
    for (int j = 0; j < 2; ++j) acc[i][j] = (f32x4){0.f, 0.f, 0.f, 0.f};

#pragma unroll
  for (int kk = 0; kk < 8; ++kk) {            // 8 x K32, no barriers
    bf16x8 af[2], bf[2];
#pragma unroll
    for (int i = 0; i < 2; ++i)
      af[i] = *(const bf16x8*)&w_eff[(size_t)(wave_o + i * 16 + l15) * 256 + kk * 32 + quad * 8];
#pragma unroll
    for (int j = 0; j < 2; ++j)
      bf[j] = *(const bf16x8*)&B_lds[(j * 16 + l15) * BSTRIDE + kk * 32 + quad * 8];
#pragma unroll
    for (int i = 0; i < 2; ++i)
#pragma unroll
      for (int j = 0; j < 2; ++j)
        acc[i][j] = __builtin_amdgcn_mfma_f32_16x16x32_bf16(af[i], bf[j], acc[i][j], 0, 0, 0);
  }

  // epilogue: bias + SiLU, fp32 NCHW stores
  float* outb = out + (size_t)b * 256 * 4096 + h * 64 + half * 32;
#pragma unroll
  for (int i = 0; i < 2; ++i) {
#pragma unroll
    for (int r = 0; r < 4; ++r) {
      const int o = wave_o + i * 16 + quad * 4 + r;
      const float bo = bias2[o];
#pragma unroll
      for (int j = 0; j < 2; ++j) {
        const int p = j * 16 + l15;
        outb[(size_t)o * 4096 + p] = silu_f(acc[i][j][r] + bo);
      }
    }
  }
}

extern "C" void kernel_launch(void* const* d_in, const int* in_sizes, int n_in,
                              void* d_out, int out_size, void* d_ws, size_t ws_size,
                              hipStream_t stream) {
  const float* x         = (const float*)d_in[0];
  const float* w_experts = (const float*)d_in[1];
  const float* bn_gamma  = (const float*)d_in[2];
  const float* bn_beta   = (const float*)d_in[3];
  const float* bn_mean   = (const float*)d_in[4];
  const float* bn_var    = (const float*)d_in[5];
  const float* scales    = (const float*)d_in[6];
  const float* w_out     = (const float*)d_in[7];
  const float* out_gamma = (const float*)d_in[8];
  const float* out_beta  = (const float*)d_in[9];
  const float* out_mean  = (const float*)d_in[10];
  const float* out_var   = (const float*)d_in[11];
  float* out = (float*)d_out;

  char* ws = (char*)d_ws;
  float* eff_kernel = (float*)(ws);             // 9216 B
  float* eff_bias   = (float*)(ws + 9216);      // 1 KiB
  __bf16* w_eff     = (__bf16*)(ws + 10240);    // 128 KiB
  float* bias2      = (float*)(ws + 141312);    // 1 KiB

  hipLaunchKernelGGL(prep_kernel, dim3(257), dim3(256), 0, stream,
                     w_experts, bn_gamma, bn_beta, bn_mean, bn_var, scales,
                     w_out, out_gamma, out_beta, out_mean, out_var,
                     eff_kernel, eff_bias, w_eff, bias2);
  hipLaunchKernelGGL(fused_kernel, dim3(1024), dim3(512), 0, stream,
                     x, eff_kernel, eff_bias, w_eff, bias2, out);
}

// Round 7
// 134.428 us; speedup vs baseline: 1.0034x; 1.0034x over previous
//
#include <hip/hip_runtime.h>

#define EPS 1e-5f

typedef __attribute__((ext_vector_type(8))) __bf16 bf16x8;
typedef __attribute__((ext_vector_type(4))) float f32x4;

__device__ __forceinline__ float silu_f(float v) {
  return v * __builtin_amdgcn_rcpf(1.f + __expf(-v));
}

// ---------------- prep: fold BN + scales ----------------
__global__ __launch_bounds__(256) void prep_kernel(
    const float* __restrict__ w_experts, const float* __restrict__ bn_gamma,
    const float* __restrict__ bn_beta, const float* __restrict__ bn_mean,
    const float* __restrict__ bn_var, const float* __restrict__ scales,
    const float* __restrict__ w_out, const float* __restrict__ out_gamma,
    const float* __restrict__ out_beta, const float* __restrict__ out_mean,
    const float* __restrict__ out_var,
    float* __restrict__ eff_kernel, float* __restrict__ eff_bias,
    __bf16* __restrict__ w_eff, float* __restrict__ bias2)
{
  const int t = threadIdx.x;
  if (blockIdx.x == 0) {
    const int c = t;
    float k9[9];
#pragma unroll
    for (int r = 0; r < 9; ++r) k9[r] = 0.f;
    float bias = 0.f;
    for (int e = 0; e < 9; ++e) {
      const int ec = e * 256 + c;
      const float tt = bn_gamma[ec] * rsqrtf(bn_var[ec] + EPS);
      const float sc = scales[ec];
      const float es = tt * sc;
      bias += (bn_beta[ec] - bn_mean[ec] * tt) * sc;
      const float* wp = w_experts + (size_t)ec * 9;
#pragma unroll
      for (int r = 0; r < 9; ++r) k9[r] += es * wp[r];
    }
#pragma unroll
    for (int r = 0; r < 9; ++r) eff_kernel[c * 9 + r] = k9[r];
    eff_bias[c] = bias;
    const float t2 = out_gamma[c] * rsqrtf(out_var[c] + EPS);
    bias2[c] = out_beta[c] - out_mean[c] * t2;
  } else {
    const int i = (blockIdx.x - 1) * 256 + t;   // 0..65535
    const int o = i >> 8;
    const float t2 = out_gamma[o] * rsqrtf(out_var[o] + EPS);
    w_eff[i] = (__bf16)(w_out[i] * t2);
  }
}

// ---------------- fused: depthwise 3x3 + SiLU -> LDS -> MFMA out-proj -------
// grid 1024 = (b | (half,h) << 3): half-row blocks (32 px), 512 threads.
// Phase 1 is BRANCH-FREE: clamped addresses + multiplicative edge masks, so
// all loads are unconditional and the compiler can batch them (MLP fix).
#define BSTRIDE 258   // pixel stride in B_lds (129 dw == 1 mod 8: conflict-free writes)
__global__ __launch_bounds__(512, 4) void fused_kernel(
    const float* __restrict__ x, const float* __restrict__ eff_kernel,
    const float* __restrict__ eff_bias, const __bf16* __restrict__ w_eff,
    const float* __restrict__ bias2, float* __restrict__ out)
{
  __shared__ __align__(16) __bf16 B_lds[32 * BSTRIDE];  // [local pixel][ch]
  __shared__ float kern_s[256 * 9];
  __shared__ float bias_s[256];
  const int t = threadIdx.x;
  const int id = blockIdx.x;
  const int b = id & 7;                 // XCD-local batch
  const int rest = id >> 3;             // 0..127
  const int h = rest >> 1;              // 0..63
  const int half = rest & 1;            // 0/1 -> pixel offset 0/32

  for (int i = t; i < 2304; i += 512) kern_s[i] = eff_kernel[i];
  if (t < 256) bias_s[t] = eff_bias[t];
  __syncthreads();

  const int lane = t & 63;
  const int wv = t >> 6;                // 0..7
  const int chl = lane >> 3;            // 0..7 channel sub-index
  const int pxl = lane & 7;             // 0..7, each covers 4 px via float4
  const int w0 = half * 32 + pxl * 4;   // global w of first pixel

  // clamped coords (always-valid addresses) + zero masks
  const int hm1 = (h > 0) ? h - 1 : 0;
  const int hp1 = (h < 63) ? h + 1 : 63;
  const float um = (h > 0) ? 1.f : 0.f;        // wave-uniform
  const float dm = (h < 63) ? 1.f : 0.f;
  const int wl = (w0 > 0) ? w0 - 1 : 0;
  const int wr = (w0 + 4 < 64) ? w0 + 4 : 63;
  const float lm = (w0 > 0) ? 1.f : 0.f;       // per-lane
  const float rm = (w0 + 4 < 64) ? 1.f : 0.f;

#pragma unroll
  for (int it = 0; it < 4; ++it) {
    const int ch = it * 64 + wv * 8 + chl;       // 0..255
    const float* xc = x + (size_t)(b * 256 + ch) * 4096;
    const float* r0 = xc + hm1 * 64;
    const float* r1 = xc + h * 64;
    const float* r2 = xc + hp1 * 64;

    // 9 unconditional loads (3 x dwordx4 + 6 x dword) — batchable
    const float4 m0 = *(const float4*)(r0 + w0);
    const float4 m1 = *(const float4*)(r1 + w0);
    const float4 m2 = *(const float4*)(r2 + w0);
    const float e00 = r0[wl], e05 = r0[wr];
    const float e10 = r1[wl], e15 = r1[wr];
    const float e20 = r2[wl], e25 = r2[wr];

    // top/bottom masks folded into the kernel taps (wave-uniform)
    const float* kp = &kern_s[ch * 9];
    const float k0 = kp[0] * um, k1 = kp[1] * um, k2 = kp[2] * um;
    const float k3 = kp[3],      k4 = kp[4],      k5 = kp[5];
    const float k6 = kp[6] * dm, k7 = kp[7] * dm, k8 = kp[8] * dm;
    const float bias = bias_s[ch];

    const float row0[6] = {e00 * lm, m0.x, m0.y, m0.z, m0.w, e05 * rm};
    const float row1[6] = {e10 * lm, m1.x, m1.y, m1.z, m1.w, e15 * rm};
    const float row2[6] = {e20 * lm, m2.x, m2.y, m2.z, m2.w, e25 * rm};

#pragma unroll
    for (int j = 0; j < 4; ++j) {
      float s = bias;
      s += k0 * row0[j] + k1 * row0[j + 1] + k2 * row0[j + 2];
      s += k3 * row1[j] + k4 * row1[j + 1] + k5 * row1[j + 2];
      s += k6 * row2[j] + k7 * row2[j + 1] + k8 * row2[j + 2];
      B_lds[(pxl * 4 + j) * BSTRIDE + ch] = (__bf16)silu_f(s);
    }
  }

  // Preload ALL A-fragments (global, independent of B_lds) before the
  // barrier: they complete during the barrier's vmcnt drain.
  const int quad = lane >> 4, l15 = lane & 15;
  const int wave_o = wv * 32;
  bf16x8 af[8][2];
#pragma unroll
  for (int kk = 0; kk < 8; ++kk)
#pragma unroll
    for (int i = 0; i < 2; ++i)
      af[kk][i] = *(const bf16x8*)&w_eff[(size_t)(wave_o + i * 16 + l15) * 256 + kk * 32 + quad * 8];

  __syncthreads();

  // ---- GEMM phase: M=256(o) x N=32(p) x K=256(c); 8 waves of 32(o) x 32(p)
  f32x4 acc[2][2];
#pragma unroll
  for (int i = 0; i < 2; ++i)
#pragma unroll
    for (int j = 0; j < 2; ++j) acc[i][j] = (f32x4){0.f, 0.f, 0.f, 0.f};

#pragma unroll
  for (int kk = 0; kk < 8; ++kk) {            // 8 x K32, no barriers
    bf16x8 bf[2];
#pragma unroll
    for (int j = 0; j < 2; ++j)
      bf[j] = *(const bf16x8*)&B_lds[(j * 16 + l15) * BSTRIDE + kk * 32 + quad * 8];
#pragma unroll
    for (int i = 0; i < 2; ++i)
#pragma unroll
      for (int j = 0; j < 2; ++j)
        acc[i][j] = __builtin_amdgcn_mfma_f32_16x16x32_bf16(af[kk][i], bf[j], acc[i][j], 0, 0, 0);
  }

  // epilogue: bias + SiLU, fp32 NCHW stores
  float* outb = out + (size_t)b * 256 * 4096 + h * 64 + half * 32;
#pragma unroll
  for (int i = 0; i < 2; ++i) {
#pragma unroll
    for (int r = 0; r < 4; ++r) {
      const int o = wave_o + i * 16 + quad * 4 + r;
      const float bo = bias2[o];
#pragma unroll
      for (int j = 0; j < 2; ++j) {
        const int p = j * 16 + l15;
        outb[(size_t)o * 4096 + p] = silu_f(acc[i][j][r] + bo);
      }
    }
  }
}

extern "C" void kernel_launch(void* const* d_in, const int* in_sizes, int n_in,
                              void* d_out, int out_size, void* d_ws, size_t ws_size,
                              hipStream_t stream) {
  const float* x         = (const float*)d_in[0];
  const float* w_experts = (const float*)d_in[1];
  const float* bn_gamma  = (const float*)d_in[2];
  const float* bn_beta   = (const float*)d_in[3];
  const float* bn_mean   = (const float*)d_in[4];
  const float* bn_var    = (const float*)d_in[5];
  const float* scales    = (const float*)d_in[6];
  const float* w_out     = (const float*)d_in[7];
  const float* out_gamma = (const float*)d_in[8];
  const float* out_beta  = (const float*)d_in[9];
  const float* out_mean  = (const float*)d_in[10];
  const float* out_var   = (const float*)d_in[11];
  float* out = (float*)d_out;

  char* ws = (char*)d_ws;
  float* eff_kernel = (float*)(ws);             // 9216 B
  float* eff_bias   = (float*)(ws + 9216);      // 1 KiB
  __bf16* w_eff     = (__bf16*)(ws + 10240);    // 128 KiB
  float* bias2      = (float*)(ws + 141312);    // 1 KiB

  hipLaunchKernelGGL(prep_kernel, dim3(257), dim3(256), 0, stream,
                     w_experts, bn_gamma, bn_beta, bn_mean, bn_var, scales,
                     w_out, out_gamma, out_beta, out_mean, out_var,
                     eff_kernel, eff_bias, w_eff, bias2);
  hipLaunchKernelGGL(fused_kernel, dim3(1024), dim3(512), 0, stream,
                     x, eff_kernel, eff_bias, w_eff, bias2, out);
}